// Round 5
// baseline (2639.889 us; speedup 1.0000x reference)
//
#include <hip/hip_runtime.h>

// B=16, N=8192, C1=64, C2=128, C3=256, NP=32
// Bit-replication of numpy fp32 reference: sequential accumulation, ascending
// contraction index, NO FMA (__fmul_rn/__fadd_rn), correctly-rounded sqrt/div,
// top-k ties -> lower index. DO NOT introduce FMA/fp64 — ordering breaks.

__device__ __forceinline__ float bf16rne(float x) {
    unsigned u = __float_as_uint(x);
    u = (u + 0x7FFFu + ((u >> 16) & 1u)) & 0xFFFF0000u;
    return __uint_as_float(u);
}

// ---------------- scales: s = g / sqrt(v + 1e-5f), exact fp32 ----------------
__global__ void scales_kernel(const float* __restrict__ g1, const float* __restrict__ v1,
                              const float* __restrict__ g2, const float* __restrict__ v2,
                              const float* __restrict__ g3, const float* __restrict__ v3,
                              float* __restrict__ s) {
    int t = threadIdx.x;
    if (t < 64)       s[t] = __fdiv_rn(g1[t],       __fsqrt_rn(__fadd_rn(v1[t],       1e-5f)));
    else if (t < 192) s[t] = __fdiv_rn(g2[t - 64],  __fsqrt_rn(__fadd_rn(v2[t - 64],  1e-5f)));
    else if (t < 448) s[t] = __fdiv_rn(g3[t - 192], __fsqrt_rn(__fadd_rn(v3[t - 192], 1e-5f)));
}

// ---------------- w3 transpose: w3t[ci][o] = w3[o][ci] ----------------
__global__ void w3t_kernel(const float* __restrict__ w3, float* __restrict__ w3t) {
    int i = blockIdx.x * 256 + threadIdx.x;     // 32768 total
    int o = i >> 7, ci = i & 127;
    w3t[ci * 256 + o] = w3[o * 128 + ci];
}

// ---------------- fused MLP, numpy-exact fp32, layers 2+3 fused ----------------
// 2 threads per point: half=0 -> out channels [0,128), half=1 -> [128,256).
// h2 never materialized: per c2 (ascending) compute h2v then accumulate into
// 128 register accumulators. Zero LDS.
__global__ __launch_bounds__(256, 2) void mlp_kernel(
        const float* __restrict__ x,
        const float* __restrict__ w1, const float* __restrict__ b1,
        const float* __restrict__ m1, const float* __restrict__ be1,
        const float* __restrict__ w2, const float* __restrict__ b2,
        const float* __restrict__ m2, const float* __restrict__ be2,
        const float* __restrict__ w3t, const float* __restrict__ b3,
        const float* __restrict__ m3, const float* __restrict__ be3,
        const float* __restrict__ sc,
        float* __restrict__ h) {
    const float* s1 = sc;
    const float* s2 = sc + 64;
    const float* s3 = sc + 192;

    int t    = threadIdx.x;
    int blk  = blockIdx.x & 511;
    int half = blockIdx.x >> 9;          // 0 or 1
    int pt   = blk * 256 + t;
    int b    = pt >> 13;
    int n    = pt & 8191;

    const float* xb = x + (size_t)b * 24576 + n;
    float x0 = xb[0], x1 = xb[8192], x2 = xb[16384];

    // layer 1: 3 -> 64 (acc = ((w0*x0 + w1*x1) + w2*x2), no FMA)
    float h1[64];
#pragma unroll
    for (int o = 0; o < 64; ++o) {
        float acc = __fmul_rn(w1[o * 3 + 0], x0);
        acc = __fadd_rn(acc, __fmul_rn(w1[o * 3 + 1], x1));
        acc = __fadd_rn(acc, __fmul_rn(w1[o * 3 + 2], x2));
        float hpb = __fadd_rn(acc, b1[o]);
        float tt  = __fsub_rn(hpb, m1[o]);
        float r   = __fadd_rn(__fmul_rn(tt, s1[o]), be1[o]);
        h1[o] = fmaxf(r, 0.0f);
    }

    // layers 2+3 fused: acc[j] = sum_{c2 asc} w3[half*128+j][c2] * h2[c2]
    float acc[128];
#pragma unroll
    for (int j = 0; j < 128; ++j) acc[j] = 0.0f;

    const float* w3h = w3t + half * 128;          // row stride 256
#pragma unroll 2
    for (int c2 = 0; c2 < 128; ++c2) {
        const float* wr = w2 + c2 * 64;
        float a = 0.0f;
#pragma unroll
        for (int c1 = 0; c1 < 64; ++c1)
            a = __fadd_rn(a, __fmul_rn(wr[c1], h1[c1]));
        float hpb = __fadd_rn(a, b2[c2]);
        float tt  = __fsub_rn(hpb, m2[c2]);
        float h2v = fmaxf(__fadd_rn(__fmul_rn(tt, s2[c2]), be2[c2]), 0.0f);

        const float* w3r = w3h + (size_t)c2 * 256;
#pragma unroll
        for (int j = 0; j < 128; ++j)
            acc[j] = __fadd_rn(acc[j], __fmul_rn(w3r[j], h2v));
    }

    // epilogue BN (no relu) + store
    float* hb = h + (size_t)b * 2097152 + (size_t)half * 128 * 8192 + n;
#pragma unroll 8
    for (int j = 0; j < 128; ++j) {
        int o = half * 128 + j;
        float hpb = __fadd_rn(acc[j], b3[o]);
        float tt  = __fsub_rn(hpb, m3[o]);
        float r   = __fadd_rn(__fmul_rn(tt, s3[o]), be3[o]);
        hb[(size_t)j * 8192] = r;
    }
}

// ---------------- top-32 per row, fp32 keys, ties -> lower index ----------------
__global__ __launch_bounds__(256) void topk_kernel(const float* __restrict__ h,
                                                   int* __restrict__ idx_out) {
    __shared__ unsigned long long keys[8192];
    __shared__ unsigned long long wmax[4];

    int row = blockIdx.x;
    const float* hr = h + (size_t)row * 8192;
    int t = threadIdx.x;

    for (int i = t; i < 8192; i += 256) {
        unsigned u = __float_as_uint(hr[i]);
        u = (u & 0x80000000u) ? ~u : (u | 0x80000000u);   // monotonic map
        keys[i] = ((unsigned long long)u << 13) | (unsigned)(8191 - i);
    }
    __syncthreads();

    for (int pass = 0; pass < 32; ++pass) {
        unsigned long long m = 0ull;
#pragma unroll
        for (int j = 0; j < 32; ++j) {
            unsigned long long k = keys[t + j * 256];
            m = (k > m) ? k : m;
        }
#pragma unroll
        for (int s = 1; s < 64; s <<= 1) {
            unsigned long long o = __shfl_xor(m, s, 64);
            m = (o > m) ? o : m;
        }
        if ((t & 63) == 0) wmax[t >> 6] = m;
        __syncthreads();
        if (t == 0) {
            unsigned long long g = wmax[0];
            g = (wmax[1] > g) ? wmax[1] : g;
            g = (wmax[2] > g) ? wmax[2] : g;
            g = (wmax[3] > g) ? wmax[3] : g;
            int i = 8191 - (int)(g & 8191ull);
            idx_out[row * 32 + pass] = i;
            keys[i] = 0ull;
        }
        __syncthreads();
    }
}

// ---------------- gather: out[b,cf,k,cs] = bf16rne(h[b,cf,idx[b,cs,k]]) ----------------
__global__ __launch_bounds__(256) void gather_kernel(const float* __restrict__ h,
                                                     const int* __restrict__ idx,
                                                     float* __restrict__ out) {
    int id = blockIdx.x;
    int q  = id & 3;
    int k  = (id >> 2) & 31;
    int b  = id >> 7;
    int cs = threadIdx.x;

    int i = idx[(b * 256 + cs) * 32 + k];
    const float* hb = h + (size_t)b * 2097152;
    float* ob = out + (size_t)b * 2097152 + (size_t)k * 256 + cs;

#pragma unroll 4
    for (int cf = q * 64; cf < q * 64 + 64; ++cf) {
        ob[(size_t)cf * 8192] = bf16rne(hb[(size_t)cf * 8192 + i]);
    }
}

extern "C" void kernel_launch(void* const* d_in, const int* in_sizes, int n_in,
                              void* d_out, int out_size, void* d_ws, size_t ws_size,
                              hipStream_t stream) {
    const float* x   = (const float*)d_in[0];
    const float* w1  = (const float*)d_in[1];
    const float* b1  = (const float*)d_in[2];
    const float* g1  = (const float*)d_in[3];
    const float* be1 = (const float*)d_in[4];
    const float* m1  = (const float*)d_in[5];
    const float* v1  = (const float*)d_in[6];
    const float* w2  = (const float*)d_in[7];
    const float* b2  = (const float*)d_in[8];
    const float* g2  = (const float*)d_in[9];
    const float* be2 = (const float*)d_in[10];
    const float* m2  = (const float*)d_in[11];
    const float* v2  = (const float*)d_in[12];
    const float* w3  = (const float*)d_in[13];
    const float* b3  = (const float*)d_in[14];
    const float* g3  = (const float*)d_in[15];
    const float* be3 = (const float*)d_in[16];
    const float* m3  = (const float*)d_in[17];
    const float* v3  = (const float*)d_in[18];

    char* ws = (char*)d_ws;
    float* h    = (float*)(ws);                  // 134,217,728 B
    int*   idxb = (int*)(ws + 134217728);        //     524,288 B
    float* sc   = (float*)(ws + 134742016);      //       1,792 B
    float* w3t  = (float*)(ws + 134743808);      //     131,072 B

    scales_kernel<<<1, 448, 0, stream>>>(g1, v1, g2, v2, g3, v3, sc);
    w3t_kernel<<<128, 256, 0, stream>>>(w3, w3t);
    mlp_kernel<<<1024, 256, 0, stream>>>(x, w1, b1, m1, be1,
                                         w2, b2, m2, be2,
                                         w3t, b3, m3, be3, sc, h);
    topk_kernel<<<4096, 256, 0, stream>>>(h, idxb);
    gather_kernel<<<2048, 256, 0, stream>>>(h, idxb, (float*)d_out);
}

// Round 6
// 718.523 us; speedup vs baseline: 3.6740x; 3.6740x over previous
//
#include <hip/hip_runtime.h>

// B=16, N=8192, C1=64, C2=128, C3=256, NP=32
// Bit-replication of numpy fp32 reference: sequential accumulation, ascending
// contraction index, NO FMA (__fmul_rn/__fadd_rn), correctly-rounded sqrt/div,
// top-k ties -> lower index. DO NOT introduce FMA/fp64 — ordering breaks.
// RULE: never runtime-index a register array (round-5 spill: 674->2350us).

using v4f = __attribute__((ext_vector_type(4))) float;

__device__ __forceinline__ float bf16rne(float x) {
    unsigned u = __float_as_uint(x);
    u = (u + 0x7FFFu + ((u >> 16) & 1u)) & 0xFFFF0000u;
    return __uint_as_float(u);
}

// ---------------- scales: s = g / sqrt(v + 1e-5f), exact fp32 ----------------
__global__ void scales_kernel(const float* __restrict__ g1, const float* __restrict__ v1,
                              const float* __restrict__ g2, const float* __restrict__ v2,
                              const float* __restrict__ g3, const float* __restrict__ v3,
                              float* __restrict__ s) {
    int t = threadIdx.x;
    if (t < 64)       s[t] = __fdiv_rn(g1[t],       __fsqrt_rn(__fadd_rn(v1[t],       1e-5f)));
    else if (t < 192) s[t] = __fdiv_rn(g2[t - 64],  __fsqrt_rn(__fadd_rn(v2[t - 64],  1e-5f)));
    else if (t < 448) s[t] = __fdiv_rn(g3[t - 192], __fsqrt_rn(__fadd_rn(v3[t - 192], 1e-5f)));
}

// ---------------- layers 1+2: x -> h2q[32][131072] float4 (in d_out scratch) ----------------
__global__ __launch_bounds__(256) void mlp12_kernel(
        const float* __restrict__ x,
        const float* __restrict__ w1, const float* __restrict__ b1,
        const float* __restrict__ m1, const float* __restrict__ be1,
        const float* __restrict__ w2, const float* __restrict__ b2,
        const float* __restrict__ m2, const float* __restrict__ be2,
        const float* __restrict__ sc,
        float* __restrict__ h2g) {
    const float* s1 = sc;
    const float* s2 = sc + 64;

    int t  = threadIdx.x;
    int pt = blockIdx.x * 256 + t;
    int b  = pt >> 13;
    int n  = pt & 8191;

    const float* xb = x + (size_t)b * 24576 + n;
    float x0 = xb[0], x1 = xb[8192], x2 = xb[16384];

    // layer 1: 3 -> 64 (static regs)
    float h1[64];
#pragma unroll
    for (int o = 0; o < 64; ++o) {
        float acc = __fmul_rn(w1[o * 3 + 0], x0);
        acc = __fadd_rn(acc, __fmul_rn(w1[o * 3 + 1], x1));
        acc = __fadd_rn(acc, __fmul_rn(w1[o * 3 + 2], x2));
        float hpb = __fadd_rn(acc, b1[o]);
        float tt  = __fsub_rn(hpb, m1[o]);
        float r   = __fadd_rn(__fmul_rn(tt, s1[o]), be1[o]);
        h1[o] = fmaxf(r, 0.0f);
    }

    // layer 2: 64 -> 128, scalar h2v straight to global (16B-stride lanes, L2 merges)
    for (int c2 = 0; c2 < 128; ++c2) {
        const float* wr = w2 + c2 * 64;
        float a = 0.0f;
#pragma unroll
        for (int c1 = 0; c1 < 64; ++c1)
            a = __fadd_rn(a, __fmul_rn(wr[c1], h1[c1]));
        float hpb = __fadd_rn(a, b2[c2]);
        float tt  = __fsub_rn(hpb, m2[c2]);
        float h2v = fmaxf(__fadd_rn(__fmul_rn(tt, s2[c2]), be2[c2]), 0.0f);
        h2g[(size_t)((c2 >> 2) * 131072 + pt) * 4 + (c2 & 3)] = h2v;
    }
}

// ---------------- layer 3: h2q -> h[16,256,8192] ----------------
__global__ __launch_bounds__(256, 2) void mlp3_kernel(
        const float* __restrict__ h2g,
        const float* __restrict__ w3, const float* __restrict__ b3,
        const float* __restrict__ m3, const float* __restrict__ be3,
        const float* __restrict__ sc,
        float* __restrict__ h) {
    const float* s3 = sc + 192;

    int t  = threadIdx.x;
    int pt = blockIdx.x * 256 + t;
    int b  = pt >> 13;
    int n  = pt & 8191;

    // h2 row into 32 static float4 regs (all indices compile-time)
    v4f r[32];
    const v4f* src = (const v4f*)h2g;
#pragma unroll
    for (int q = 0; q < 32; ++q) r[q] = src[(size_t)q * 131072 + pt];

    float* hb = h + (size_t)b * 2097152 + n;
    for (int o4 = 0; o4 < 256; o4 += 4) {
        const float* wr0 = w3 + (size_t)(o4 + 0) * 128;
        const float* wr1 = w3 + (size_t)(o4 + 1) * 128;
        const float* wr2 = w3 + (size_t)(o4 + 2) * 128;
        const float* wr3 = w3 + (size_t)(o4 + 3) * 128;
        float a0 = 0.f, a1 = 0.f, a2 = 0.f, a3 = 0.f;
#pragma unroll
        for (int c2 = 0; c2 < 128; ++c2) {
            float hv = r[c2 >> 2][c2 & 3];
            a0 = __fadd_rn(a0, __fmul_rn(wr0[c2], hv));
            a1 = __fadd_rn(a1, __fmul_rn(wr1[c2], hv));
            a2 = __fadd_rn(a2, __fmul_rn(wr2[c2], hv));
            a3 = __fadd_rn(a3, __fmul_rn(wr3[c2], hv));
        }
#pragma unroll
        for (int j = 0; j < 4; ++j) {
            float aj = (j == 0) ? a0 : (j == 1) ? a1 : (j == 2) ? a2 : a3;
            int o = o4 + j;
            float hpb = __fadd_rn(aj, b3[o]);
            float tt  = __fsub_rn(hpb, m3[o]);
            float rr  = __fadd_rn(__fmul_rn(tt, s3[o]), be3[o]);
            hb[(size_t)o * 8192] = rr;
        }
    }
}

// ---------------- top-32 per row: cached local-max tournament ----------------
__global__ __launch_bounds__(256) void topk_kernel(const float* __restrict__ h,
                                                   int* __restrict__ idx_out) {
    __shared__ unsigned long long keys[8192];
    __shared__ unsigned long long wmax[4];

    int row = blockIdx.x;
    const float* hr = h + (size_t)row * 8192;
    int t = threadIdx.x;

    unsigned long long lm = 0ull;   // cached max over this thread's 32 slots
    for (int j = 0; j < 32; ++j) {
        int i = t + j * 256;
        unsigned u = __float_as_uint(hr[i]);
        u = (u & 0x80000000u) ? ~u : (u | 0x80000000u);   // monotonic map
        unsigned long long k = ((unsigned long long)u << 13) | (unsigned)(8191 - i);
        keys[i] = k;
        lm = (k > lm) ? k : lm;
    }
    __syncthreads();

    for (int pass = 0; pass < 32; ++pass) {
        unsigned long long m = lm;
#pragma unroll
        for (int s = 1; s < 64; s <<= 1) {
            unsigned long long o = __shfl_xor(m, s, 64);
            m = (o > m) ? o : m;
        }
        if ((t & 63) == 0) wmax[t >> 6] = m;
        __syncthreads();
        unsigned long long g = wmax[0];
        g = (wmax[1] > g) ? wmax[1] : g;
        g = (wmax[2] > g) ? wmax[2] : g;
        g = (wmax[3] > g) ? wmax[3] : g;

        if (lm == g) {                       // unique winner (key embeds index)
            int i = 8191 - (int)(g & 8191ull);
            keys[i] = 0ull;
            unsigned long long nm = 0ull;
            for (int j = 0; j < 32; ++j) {
                unsigned long long k = keys[t + j * 256];
                nm = (k > nm) ? k : nm;
            }
            lm = nm;
        }
        if (t == 0) idx_out[row * 32 + pass] = 8191 - (int)(g & 8191ull);
        __syncthreads();
    }
}

// ---------------- gather: block=(b,cf); h row stays L1-resident ----------------
__global__ __launch_bounds__(256) void gather_kernel(const float* __restrict__ h,
                                                     const int* __restrict__ idx,
                                                     float* __restrict__ out) {
    __shared__ int idxs[8192];   // idx[b][cs][k], j = cs*32+k

    int blk = blockIdx.x;
    int b   = blk >> 8;
    int cf  = blk & 255;
    int t   = threadIdx.x;

    for (int j = t; j < 8192; j += 256) idxs[j] = idx[b * 8192 + j];
    __syncthreads();

    const float* hrow = h + (size_t)b * 2097152 + (size_t)cf * 8192;
    float* ob = out + (size_t)b * 2097152 + (size_t)cf * 8192;

#pragma unroll
    for (int rep = 0; rep < 32; ++rep) {
        int elem = rep * 256 + t;       // = k*256 + cs
        int k  = elem >> 8;
        int cs = elem & 255;
        int i  = idxs[cs * 32 + k];
        ob[elem] = bf16rne(hrow[i]);
    }
}

extern "C" void kernel_launch(void* const* d_in, const int* in_sizes, int n_in,
                              void* d_out, int out_size, void* d_ws, size_t ws_size,
                              hipStream_t stream) {
    const float* x   = (const float*)d_in[0];
    const float* w1  = (const float*)d_in[1];
    const float* b1  = (const float*)d_in[2];
    const float* g1  = (const float*)d_in[3];
    const float* be1 = (const float*)d_in[4];
    const float* m1  = (const float*)d_in[5];
    const float* v1  = (const float*)d_in[6];
    const float* w2  = (const float*)d_in[7];
    const float* b2  = (const float*)d_in[8];
    const float* g2  = (const float*)d_in[9];
    const float* be2 = (const float*)d_in[10];
    const float* m2  = (const float*)d_in[11];
    const float* v2  = (const float*)d_in[12];
    const float* w3  = (const float*)d_in[13];
    const float* b3  = (const float*)d_in[14];
    const float* g3  = (const float*)d_in[15];
    const float* be3 = (const float*)d_in[16];
    const float* m3  = (const float*)d_in[17];
    const float* v3  = (const float*)d_in[18];

    char* ws = (char*)d_ws;
    float* h    = (float*)(ws);                  // 134,217,728 B
    int*   idxb = (int*)(ws + 134217728);        //     524,288 B
    float* sc   = (float*)(ws + 134742016);      //       1,792 B
    float* h2g  = (float*)d_out;                 // 67,108,864 B scratch in d_out (dead until gather)

    scales_kernel<<<1, 448, 0, stream>>>(g1, v1, g2, v2, g3, v3, sc);
    mlp12_kernel<<<512, 256, 0, stream>>>(x, w1, b1, m1, be1,
                                          w2, b2, m2, be2, sc, h2g);
    mlp3_kernel<<<512, 256, 0, stream>>>(h2g, w3, b3, m3, be3, sc, h);
    topk_kernel<<<4096, 256, 0, stream>>>(h, idxb);
    gather_kernel<<<4096, 256, 0, stream>>>(h, idxb, (float*)d_out);
}

// Round 7
// 669.744 us; speedup vs baseline: 3.9416x; 1.0728x over previous
//
#include <hip/hip_runtime.h>

// B=16, N=8192, C1=64, C2=128, C3=256, NP=32
// Bit-replication of numpy fp32 reference: sequential accumulation, ascending
// contraction index, NO FMA (__fmul_rn/__fadd_rn), correctly-rounded sqrt/div,
// top-k ties -> lower index. DO NOT introduce FMA/fp64 — ordering breaks.
// RULE: never runtime-index a register array (round-5 spill: 674->2350us).
// RULE: weights via float4 loads — scalar uniform loads are VMEM-issue-bound
//       (round-6 mlp3: 1 load per 2 VALU ops -> 3.3x VALU floor).

using v4f = __attribute__((ext_vector_type(4))) float;

__device__ __forceinline__ float bf16rne(float x) {
    unsigned u = __float_as_uint(x);
    u = (u + 0x7FFFu + ((u >> 16) & 1u)) & 0xFFFF0000u;
    return __uint_as_float(u);
}

// ---------------- scales: s = g / sqrt(v + 1e-5f), exact fp32 ----------------
__global__ void scales_kernel(const float* __restrict__ g1, const float* __restrict__ v1,
                              const float* __restrict__ g2, const float* __restrict__ v2,
                              const float* __restrict__ g3, const float* __restrict__ v3,
                              float* __restrict__ s) {
    int t = threadIdx.x;
    if (t < 64)       s[t] = __fdiv_rn(g1[t],       __fsqrt_rn(__fadd_rn(v1[t],       1e-5f)));
    else if (t < 192) s[t] = __fdiv_rn(g2[t - 64],  __fsqrt_rn(__fadd_rn(v2[t - 64],  1e-5f)));
    else if (t < 448) s[t] = __fdiv_rn(g3[t - 192], __fsqrt_rn(__fadd_rn(v3[t - 192], 1e-5f)));
}

// ---------------- layers 1+2: x -> h2q[32][131072] float4 (in d_out scratch) ----------------
__global__ __launch_bounds__(256) void mlp12_kernel(
        const float* __restrict__ x,
        const float* __restrict__ w1, const float* __restrict__ b1,
        const float* __restrict__ m1, const float* __restrict__ be1,
        const float* __restrict__ w2, const float* __restrict__ b2,
        const float* __restrict__ m2, const float* __restrict__ be2,
        const float* __restrict__ sc,
        float* __restrict__ h2g) {
    const float* s1 = sc;
    const float* s2 = sc + 64;

    int t  = threadIdx.x;
    int pt = blockIdx.x * 256 + t;
    int b  = pt >> 13;
    int n  = pt & 8191;

    const float* xb = x + (size_t)b * 24576 + n;
    float x0 = xb[0], x1 = xb[8192], x2 = xb[16384];

    // layer 1: 3 -> 64 (static regs, exact order)
    float h1[64];
#pragma unroll
    for (int o = 0; o < 64; ++o) {
        float acc = __fmul_rn(w1[o * 3 + 0], x0);
        acc = __fadd_rn(acc, __fmul_rn(w1[o * 3 + 1], x1));
        acc = __fadd_rn(acc, __fmul_rn(w1[o * 3 + 2], x2));
        float hpb = __fadd_rn(acc, b1[o]);
        float tt  = __fsub_rn(hpb, m1[o]);
        float r   = __fadd_rn(__fmul_rn(tt, s1[o]), be1[o]);
        h1[o] = fmaxf(r, 0.0f);
    }

    // layer 2: 64 -> 128; w2 rows via float4; 4 channels buffered -> one v4f store
    v4f* dst = (v4f*)h2g;
    const v4f* w2v = (const v4f*)w2;
#pragma unroll 2
    for (int q = 0; q < 32; ++q) {
        v4f hv;
#pragma unroll
        for (int j = 0; j < 4; ++j) {
            int c2 = q * 4 + j;
            const v4f* wr = w2v + c2 * 16;       // 16 v4f = 64 floats
            float a = 0.0f;
#pragma unroll
            for (int k = 0; k < 16; ++k) {
                v4f w = wr[k];
                a = __fadd_rn(a, __fmul_rn(w.x, h1[4 * k + 0]));
                a = __fadd_rn(a, __fmul_rn(w.y, h1[4 * k + 1]));
                a = __fadd_rn(a, __fmul_rn(w.z, h1[4 * k + 2]));
                a = __fadd_rn(a, __fmul_rn(w.w, h1[4 * k + 3]));
            }
            float hpb = __fadd_rn(a, b2[c2]);
            float tt  = __fsub_rn(hpb, m2[c2]);
            hv[j] = fmaxf(__fadd_rn(__fmul_rn(tt, s2[c2]), be2[c2]), 0.0f);
        }
        dst[(size_t)q * 131072 + pt] = hv;
    }
}

// ---------------- layer 3: h2q -> h[16,256,8192] (w3 via float4) ----------------
__global__ __launch_bounds__(256, 2) void mlp3_kernel(
        const float* __restrict__ h2g,
        const float* __restrict__ w3, const float* __restrict__ b3,
        const float* __restrict__ m3, const float* __restrict__ be3,
        const float* __restrict__ sc,
        float* __restrict__ h) {
    const float* s3 = sc + 192;

    int t  = threadIdx.x;
    int pt = blockIdx.x * 256 + t;
    int b  = pt >> 13;
    int n  = pt & 8191;

    // h2 row into 32 static float4 regs (all indices compile-time)
    v4f r[32];
    const v4f* src = (const v4f*)h2g;
#pragma unroll
    for (int q = 0; q < 32; ++q) r[q] = src[(size_t)q * 131072 + pt];

    float* hb = h + (size_t)b * 2097152 + n;
    const v4f* w3v = (const v4f*)w3;
    for (int o4 = 0; o4 < 256; o4 += 4) {
        const v4f* wr0 = w3v + (size_t)(o4 + 0) * 32;
        const v4f* wr1 = w3v + (size_t)(o4 + 1) * 32;
        const v4f* wr2 = w3v + (size_t)(o4 + 2) * 32;
        const v4f* wr3 = w3v + (size_t)(o4 + 3) * 32;
        float a0 = 0.f, a1 = 0.f, a2 = 0.f, a3 = 0.f;
#pragma unroll
        for (int k = 0; k < 32; ++k) {
            v4f hv = r[k];
            v4f q0 = wr0[k];
            a0 = __fadd_rn(a0, __fmul_rn(q0.x, hv.x));
            a0 = __fadd_rn(a0, __fmul_rn(q0.y, hv.y));
            a0 = __fadd_rn(a0, __fmul_rn(q0.z, hv.z));
            a0 = __fadd_rn(a0, __fmul_rn(q0.w, hv.w));
            v4f q1 = wr1[k];
            a1 = __fadd_rn(a1, __fmul_rn(q1.x, hv.x));
            a1 = __fadd_rn(a1, __fmul_rn(q1.y, hv.y));
            a1 = __fadd_rn(a1, __fmul_rn(q1.z, hv.z));
            a1 = __fadd_rn(a1, __fmul_rn(q1.w, hv.w));
            v4f q2 = wr2[k];
            a2 = __fadd_rn(a2, __fmul_rn(q2.x, hv.x));
            a2 = __fadd_rn(a2, __fmul_rn(q2.y, hv.y));
            a2 = __fadd_rn(a2, __fmul_rn(q2.z, hv.z));
            a2 = __fadd_rn(a2, __fmul_rn(q2.w, hv.w));
            v4f q3 = wr3[k];
            a3 = __fadd_rn(a3, __fmul_rn(q3.x, hv.x));
            a3 = __fadd_rn(a3, __fmul_rn(q3.y, hv.y));
            a3 = __fadd_rn(a3, __fmul_rn(q3.z, hv.z));
            a3 = __fadd_rn(a3, __fmul_rn(q3.w, hv.w));
        }
#pragma unroll
        for (int j = 0; j < 4; ++j) {
            float aj = (j == 0) ? a0 : (j == 1) ? a1 : (j == 2) ? a2 : a3;
            int o = o4 + j;
            float hpb = __fadd_rn(aj, b3[o]);
            float tt  = __fsub_rn(hpb, m3[o]);
            float rr  = __fadd_rn(__fmul_rn(tt, s3[o]), be3[o]);
            hb[(size_t)o * 8192] = rr;
        }
    }
}

// ---------------- top-32 per row: cached local-max tournament ----------------
__global__ __launch_bounds__(256) void topk_kernel(const float* __restrict__ h,
                                                   int* __restrict__ idx_out) {
    __shared__ unsigned long long keys[8192];
    __shared__ unsigned long long wmax[4];

    int row = blockIdx.x;
    const float* hr = h + (size_t)row * 8192;
    int t = threadIdx.x;

    unsigned long long lm = 0ull;   // cached max over this thread's 32 slots
    for (int j = 0; j < 32; ++j) {
        int i = t + j * 256;
        unsigned u = __float_as_uint(hr[i]);
        u = (u & 0x80000000u) ? ~u : (u | 0x80000000u);   // monotonic map
        unsigned long long k = ((unsigned long long)u << 13) | (unsigned)(8191 - i);
        keys[i] = k;
        lm = (k > lm) ? k : lm;
    }
    __syncthreads();

    for (int pass = 0; pass < 32; ++pass) {
        unsigned long long m = lm;
#pragma unroll
        for (int s = 1; s < 64; s <<= 1) {
            unsigned long long o = __shfl_xor(m, s, 64);
            m = (o > m) ? o : m;
        }
        if ((t & 63) == 0) wmax[t >> 6] = m;
        __syncthreads();
        unsigned long long g = wmax[0];
        g = (wmax[1] > g) ? wmax[1] : g;
        g = (wmax[2] > g) ? wmax[2] : g;
        g = (wmax[3] > g) ? wmax[3] : g;

        if (lm == g) {                       // unique winner (key embeds index)
            int i = 8191 - (int)(g & 8191ull);
            keys[i] = 0ull;
            unsigned long long nm = 0ull;
            for (int j = 0; j < 32; ++j) {
                unsigned long long k = keys[t + j * 256];
                nm = (k > nm) ? k : nm;
            }
            lm = nm;
        }
        if (t == 0) idx_out[row * 32 + pass] = 8191 - (int)(g & 8191ull);
        __syncthreads();
    }
}

// ---------------- gather: block=(b,cf); h row stays L1-resident ----------------
__global__ __launch_bounds__(256) void gather_kernel(const float* __restrict__ h,
                                                     const int* __restrict__ idx,
                                                     float* __restrict__ out) {
    __shared__ int idxs[8192];   // idx[b][cs][k], j = cs*32+k

    int blk = blockIdx.x;
    int b   = blk >> 8;
    int cf  = blk & 255;
    int t   = threadIdx.x;

    for (int j = t; j < 8192; j += 256) idxs[j] = idx[b * 8192 + j];
    __syncthreads();

    const float* hrow = h + (size_t)b * 2097152 + (size_t)cf * 8192;
    float* ob = out + (size_t)b * 2097152 + (size_t)cf * 8192;

#pragma unroll
    for (int rep = 0; rep < 32; ++rep) {
        int elem = rep * 256 + t;       // = k*256 + cs
        int k  = elem >> 8;
        int cs = elem & 255;
        int i  = idxs[cs * 32 + k];
        ob[elem] = bf16rne(hrow[i]);
    }
}

extern "C" void kernel_launch(void* const* d_in, const int* in_sizes, int n_in,
                              void* d_out, int out_size, void* d_ws, size_t ws_size,
                              hipStream_t stream) {
    const float* x   = (const float*)d_in[0];
    const float* w1  = (const float*)d_in[1];
    const float* b1  = (const float*)d_in[2];
    const float* g1  = (const float*)d_in[3];
    const float* be1 = (const float*)d_in[4];
    const float* m1  = (const float*)d_in[5];
    const float* v1  = (const float*)d_in[6];
    const float* w2  = (const float*)d_in[7];
    const float* b2  = (const float*)d_in[8];
    const float* g2  = (const float*)d_in[9];
    const float* be2 = (const float*)d_in[10];
    const float* m2  = (const float*)d_in[11];
    const float* v2  = (const float*)d_in[12];
    const float* w3  = (const float*)d_in[13];
    const float* b3  = (const float*)d_in[14];
    const float* g3  = (const float*)d_in[15];
    const float* be3 = (const float*)d_in[16];
    const float* m3  = (const float*)d_in[17];
    const float* v3  = (const float*)d_in[18];

    char* ws = (char*)d_ws;
    float* h    = (float*)(ws);                  // 134,217,728 B
    int*   idxb = (int*)(ws + 134217728);        //     524,288 B
    float* sc   = (float*)(ws + 134742016);      //       1,792 B
    float* h2g  = (float*)d_out;                 // 67,108,864 B scratch in d_out (dead until gather)

    scales_kernel<<<1, 448, 0, stream>>>(g1, v1, g2, v2, g3, v3, sc);
    mlp12_kernel<<<512, 256, 0, stream>>>(x, w1, b1, m1, be1,
                                          w2, b2, m2, be2, sc, h2g);
    mlp3_kernel<<<512, 256, 0, stream>>>(h2g, w3, b3, m3, be3, sc, h);
    topk_kernel<<<4096, 256, 0, stream>>>(h, idxb);
    gather_kernel<<<4096, 256, 0, stream>>>(h, idxb, (float*)d_out);
}

// Round 8
// 632.309 us; speedup vs baseline: 4.1750x; 1.0592x over previous
//
#include <hip/hip_runtime.h>

// B=16, N=8192, C1=64, C2=128, C3=256, NP=32
// Bit-replication of numpy fp32 reference: sequential accumulation, ascending
// contraction index, NO FMA (__fmul_rn/__fadd_rn), correctly-rounded sqrt/div,
// top-k ties -> lower index. DO NOT introduce FMA/fp64 — ordering breaks.
// RULE: never runtime-index a register array (round-5 spill: 674->2350us).
// RULE: occupancy first — grid must be >= ~2048 blocks of 256 (round-7: 512
//       blocks = 2 waves/SIMD left VALUBusy at 32% regardless of load width).

using v4f = __attribute__((ext_vector_type(4))) float;

__device__ __forceinline__ float bf16rne(float x) {
    unsigned u = __float_as_uint(x);
    u = (u + 0x7FFFu + ((u >> 16) & 1u)) & 0xFFFF0000u;
    return __uint_as_float(u);
}

// ---------------- scales: s = g / sqrt(v + 1e-5f), exact fp32 ----------------
__global__ void scales_kernel(const float* __restrict__ g1, const float* __restrict__ v1,
                              const float* __restrict__ g2, const float* __restrict__ v2,
                              const float* __restrict__ g3, const float* __restrict__ v3,
                              float* __restrict__ s) {
    int t = threadIdx.x;
    if (t < 64)       s[t] = __fdiv_rn(g1[t],       __fsqrt_rn(__fadd_rn(v1[t],       1e-5f)));
    else if (t < 192) s[t] = __fdiv_rn(g2[t - 64],  __fsqrt_rn(__fadd_rn(v2[t - 64],  1e-5f)));
    else if (t < 448) s[t] = __fdiv_rn(g3[t - 192], __fsqrt_rn(__fadd_rn(v3[t - 192], 1e-5f)));
}

// ---------------- layers 1+2: x -> h2q[32][131072] float4 (in d_out scratch) ----------
// blockIdx = (ptblock<<2) | c2tile ; each thread: 1 point, 32 c2 channels.
__global__ __launch_bounds__(256) void mlp12_kernel(
        const float* __restrict__ x,
        const float* __restrict__ w1, const float* __restrict__ b1,
        const float* __restrict__ m1, const float* __restrict__ be1,
        const float* __restrict__ w2, const float* __restrict__ b2,
        const float* __restrict__ m2, const float* __restrict__ be2,
        const float* __restrict__ sc,
        float* __restrict__ h2g) {
    const float* s1 = sc;
    const float* s2 = sc + 64;

    int t    = threadIdx.x;
    int tile = blockIdx.x & 3;                 // c2 quarter
    int pt   = (blockIdx.x >> 2) * 256 + t;
    int b    = pt >> 13;
    int n    = pt & 8191;

    const float* xb = x + (size_t)b * 24576 + n;
    float x0 = xb[0], x1 = xb[8192], x2 = xb[16384];

    // layer 1: 3 -> 64 (recomputed per tile; exact order)
    float h1[64];
#pragma unroll
    for (int o = 0; o < 64; ++o) {
        float acc = __fmul_rn(w1[o * 3 + 0], x0);
        acc = __fadd_rn(acc, __fmul_rn(w1[o * 3 + 1], x1));
        acc = __fadd_rn(acc, __fmul_rn(w1[o * 3 + 2], x2));
        float hpb = __fadd_rn(acc, b1[o]);
        float tt  = __fsub_rn(hpb, m1[o]);
        float r   = __fadd_rn(__fmul_rn(tt, s1[o]), be1[o]);
        h1[o] = fmaxf(r, 0.0f);
    }

    // layer 2: 32 channels of 128; one v4f store per quad
    v4f* dst = (v4f*)h2g;
    const v4f* w2v = (const v4f*)w2;
    for (int qq = 0; qq < 8; ++qq) {
        int q = tile * 8 + qq;
        v4f hv;
#pragma unroll
        for (int j = 0; j < 4; ++j) {
            int c2 = q * 4 + j;
            const v4f* wr = w2v + c2 * 16;     // 16 v4f = 64 floats
            float a = 0.0f;
#pragma unroll
            for (int k = 0; k < 16; ++k) {
                v4f w = wr[k];
                a = __fadd_rn(a, __fmul_rn(w.x, h1[4 * k + 0]));
                a = __fadd_rn(a, __fmul_rn(w.y, h1[4 * k + 1]));
                a = __fadd_rn(a, __fmul_rn(w.z, h1[4 * k + 2]));
                a = __fadd_rn(a, __fmul_rn(w.w, h1[4 * k + 3]));
            }
            float hpb = __fadd_rn(a, b2[c2]);
            float tt  = __fsub_rn(hpb, m2[c2]);
            hv[j] = fmaxf(__fadd_rn(__fmul_rn(tt, s2[c2]), be2[c2]), 0.0f);
        }
        dst[(size_t)q * 131072 + pt] = hv;
    }
}

// ---------------- layer 3: h2q -> h[16,256,8192] ----------------
// blockIdx = (ptblock<<2) | chtile ; each thread: 1 point, 64 out channels.
// h2 streamed one v4f per k-quad; acc[64] statically unrolled.
__global__ __launch_bounds__(256) void mlp3_kernel(
        const float* __restrict__ h2g,
        const float* __restrict__ w3, const float* __restrict__ b3,
        const float* __restrict__ m3, const float* __restrict__ be3,
        const float* __restrict__ sc,
        float* __restrict__ h) {
    const float* s3 = sc + 192;

    int t    = threadIdx.x;
    int tile = blockIdx.x & 3;                 // out-channel quarter
    int pt   = (blockIdx.x >> 2) * 256 + t;
    int b    = pt >> 13;
    int n    = pt & 8191;
    int ob   = tile * 64;

    float acc[64];
#pragma unroll
    for (int j = 0; j < 64; ++j) acc[j] = 0.0f;

    const v4f* src = (const v4f*)h2g;
    const v4f* w3v = (const v4f*)w3;           // w3v[o*32 + q]

    for (int q = 0; q < 32; ++q) {
        v4f hv = src[(size_t)q * 131072 + pt];
#pragma unroll
        for (int j = 0; j < 64; ++j) {
            v4f w = w3v[(size_t)(ob + j) * 32 + q];
            acc[j] = __fadd_rn(acc[j], __fmul_rn(w.x, hv.x));
            acc[j] = __fadd_rn(acc[j], __fmul_rn(w.y, hv.y));
            acc[j] = __fadd_rn(acc[j], __fmul_rn(w.z, hv.z));
            acc[j] = __fadd_rn(acc[j], __fmul_rn(w.w, hv.w));
        }
    }

    float* hb = h + (size_t)b * 2097152 + n;
#pragma unroll
    for (int j = 0; j < 64; ++j) {
        int o = ob + j;
        float hpb = __fadd_rn(acc[j], b3[o]);
        float tt  = __fsub_rn(hpb, m3[o]);
        float rr  = __fadd_rn(__fmul_rn(tt, s3[o]), be3[o]);
        hb[(size_t)o * 8192] = rr;
    }
}

// ---------------- top-32 per row: cached local-max tournament ----------------
__global__ __launch_bounds__(256) void topk_kernel(const float* __restrict__ h,
                                                   int* __restrict__ idx_out) {
    __shared__ unsigned long long keys[8192];
    __shared__ unsigned long long wmax[4];

    int row = blockIdx.x;
    const float* hr = h + (size_t)row * 8192;
    int t = threadIdx.x;

    unsigned long long lm = 0ull;   // cached max over this thread's 32 slots
    for (int j = 0; j < 32; ++j) {
        int i = t + j * 256;
        unsigned u = __float_as_uint(hr[i]);
        u = (u & 0x80000000u) ? ~u : (u | 0x80000000u);   // monotonic map
        unsigned long long k = ((unsigned long long)u << 13) | (unsigned)(8191 - i);
        keys[i] = k;
        lm = (k > lm) ? k : lm;
    }
    __syncthreads();

    for (int pass = 0; pass < 32; ++pass) {
        unsigned long long m = lm;
#pragma unroll
        for (int s = 1; s < 64; s <<= 1) {
            unsigned long long o = __shfl_xor(m, s, 64);
            m = (o > m) ? o : m;
        }
        if ((t & 63) == 0) wmax[t >> 6] = m;
        __syncthreads();
        unsigned long long g = wmax[0];
        g = (wmax[1] > g) ? wmax[1] : g;
        g = (wmax[2] > g) ? wmax[2] : g;
        g = (wmax[3] > g) ? wmax[3] : g;

        if (lm == g) {                       // unique winner (key embeds index)
            int i = 8191 - (int)(g & 8191ull);
            keys[i] = 0ull;
            unsigned long long nm = 0ull;
            for (int j = 0; j < 32; ++j) {
                unsigned long long k = keys[t + j * 256];
                nm = (k > nm) ? k : nm;
            }
            lm = nm;
        }
        if (t == 0) idx_out[row * 32 + pass] = 8191 - (int)(g & 8191ull);
        __syncthreads();
    }
}

// ---------------- gather: block=(b,cf); h row stays L1-resident ----------------
__global__ __launch_bounds__(256) void gather_kernel(const float* __restrict__ h,
                                                     const int* __restrict__ idx,
                                                     float* __restrict__ out) {
    __shared__ int idxs[8192];   // idx[b][cs][k], j = cs*32+k

    int blk = blockIdx.x;
    int b   = blk >> 8;
    int cf  = blk & 255;
    int t   = threadIdx.x;

    for (int j = t; j < 8192; j += 256) idxs[j] = idx[b * 8192 + j];
    __syncthreads();

    const float* hrow = h + (size_t)b * 2097152 + (size_t)cf * 8192;
    float* ob = out + (size_t)b * 2097152 + (size_t)cf * 8192;

#pragma unroll
    for (int rep = 0; rep < 32; ++rep) {
        int elem = rep * 256 + t;       // = k*256 + cs
        int k  = elem >> 8;
        int cs = elem & 255;
        int i  = idxs[cs * 32 + k];
        ob[elem] = bf16rne(hrow[i]);
    }
}

extern "C" void kernel_launch(void* const* d_in, const int* in_sizes, int n_in,
                              void* d_out, int out_size, void* d_ws, size_t ws_size,
                              hipStream_t stream) {
    const float* x   = (const float*)d_in[0];
    const float* w1  = (const float*)d_in[1];
    const float* b1  = (const float*)d_in[2];
    const float* g1  = (const float*)d_in[3];
    const float* be1 = (const float*)d_in[4];
    const float* m1  = (const float*)d_in[5];
    const float* v1  = (const float*)d_in[6];
    const float* w2  = (const float*)d_in[7];
    const float* b2  = (const float*)d_in[8];
    const float* g2  = (const float*)d_in[9];
    const float* be2 = (const float*)d_in[10];
    const float* m2  = (const float*)d_in[11];
    const float* v2  = (const float*)d_in[12];
    const float* w3  = (const float*)d_in[13];
    const float* b3  = (const float*)d_in[14];
    const float* g3  = (const float*)d_in[15];
    const float* be3 = (const float*)d_in[16];
    const float* m3  = (const float*)d_in[17];
    const float* v3  = (const float*)d_in[18];

    char* ws = (char*)d_ws;
    float* h    = (float*)(ws);                  // 134,217,728 B
    int*   idxb = (int*)(ws + 134217728);        //     524,288 B
    float* sc   = (float*)(ws + 134742016);      //       1,792 B
    float* h2g  = (float*)d_out;                 // 67,108,864 B scratch in d_out (dead until gather)

    scales_kernel<<<1, 448, 0, stream>>>(g1, v1, g2, v2, g3, v3, sc);
    mlp12_kernel<<<2048, 256, 0, stream>>>(x, w1, b1, m1, be1,
                                           w2, b2, m2, be2, sc, h2g);
    mlp3_kernel<<<2048, 256, 0, stream>>>(h2g, w3, b3, m3, be3, sc, h);
    topk_kernel<<<4096, 256, 0, stream>>>(h, idxb);
    gather_kernel<<<4096, 256, 0, stream>>>(h, idxb, (float*)d_out);
}